// Round 2
// baseline (73240.033 us; speedup 1.0000x reference)
//
#include <hip/hip_runtime.h>
#include <hip/hip_bf16.h>

#define DEV __device__ __forceinline__

typedef unsigned short u16;
typedef unsigned int u32;

constexpr float INV_C  = 0.17677669529663687f;   // 1/sqrt(32)
constexpr float INV_S3 = 0.5773502691896258f;    // 1/sqrt(3)

DEV float bf2f(u32 h) { return __uint_as_float(h << 16); }
DEV u32 f2bf_bits(float f) {
  u32 u = __float_as_uint(f);
  u += 0x7fffu + ((u >> 16) & 1u);
  return u >> 16;
}

DEV void ld32f(const float* __restrict__ p, float o[32]) {
#pragma unroll
  for (int i = 0; i < 8; ++i) {
    float4 q = reinterpret_cast<const float4*>(p)[i];
    o[4*i+0]=q.x; o[4*i+1]=q.y; o[4*i+2]=q.z; o[4*i+3]=q.w;
  }
}
DEV void st32f(float* __restrict__ p, const float o[32]) {
#pragma unroll
  for (int i = 0; i < 8; ++i) {
    float4 q; q.x=o[4*i+0]; q.y=o[4*i+1]; q.z=o[4*i+2]; q.w=o[4*i+3];
    reinterpret_cast<float4*>(p)[i] = q;
  }
}
// bf16 scratch fallback (only used if ws_size is too small for f32 scratch)
DEV void ld32h(const u16* __restrict__ p, float o[32]) {
#pragma unroll
  for (int i = 0; i < 4; ++i) {
    uint4 q = reinterpret_cast<const uint4*>(p)[i];
    u32 w0=q.x, w1=q.y, w2=q.z, w3=q.w;
    o[8*i+0]=bf2f(w0 & 0xffffu); o[8*i+1]=bf2f(w0 >> 16);
    o[8*i+2]=bf2f(w1 & 0xffffu); o[8*i+3]=bf2f(w1 >> 16);
    o[8*i+4]=bf2f(w2 & 0xffffu); o[8*i+5]=bf2f(w2 >> 16);
    o[8*i+6]=bf2f(w3 & 0xffffu); o[8*i+7]=bf2f(w3 >> 16);
  }
}
DEV void st32h(u16* __restrict__ p, const float o[32]) {
#pragma unroll
  for (int i = 0; i < 16; ++i) {
    reinterpret_cast<u32*>(p)[i] = f2bf_bits(o[2*i]) | (f2bf_bits(o[2*i+1]) << 16);
  }
}

template<bool BF>
DEV void ld_scr(const void* __restrict__ ws, size_t off, float o[32]) {
  if (BF) ld32h((const u16*)ws + off, o);
  else    ld32f((const float*)ws + off, o);
}
template<bool BF>
DEV void st_scr(void* __restrict__ ws, size_t off, const float v[32]) {
  if (BF) st32h((u16*)ws + off, v);
  else    st32f((float*)ws + off, v);
}

// out[d] (+)= INV_C * sum_c in[c] * W[c*32+d]   (s @ w / einsum 'ncx,cd->ndx')
template<bool ACC>
DEV void linT(const float* __restrict__ W, const float in[32], float out[32]) {
  float acc[32];
#pragma unroll
  for (int d = 0; d < 32; ++d) acc[d] = 0.f;
#pragma unroll
  for (int c = 0; c < 32; ++c) {
#pragma unroll
    for (int d = 0; d < 32; ++d) acc[d] = __builtin_fmaf(in[c], W[c*32+d], acc[d]);
  }
#pragma unroll
  for (int d = 0; d < 32; ++d) out[d] = ACC ? __builtin_fmaf(acc[d], INV_C, out[d]) : acc[d]*INV_C;
}
// out[u] = INV_C * sum_v in[v] * W[u*32+v]      (einsum 'nv,uv->nu')
DEV void linN(const float* __restrict__ W, const float in[32], float out[32]) {
#pragma unroll
  for (int u = 0; u < 32; ++u) {
    float a = 0.f;
#pragma unroll
    for (int v = 0; v < 32; ++v) a = __builtin_fmaf(in[v], W[u*32+v], a);
    out[u] = a * INV_C;
  }
}

DEV float sigmoidf(float x) { return 1.f / (1.f + __expf(-x)); }

// Channel-wise resblock split across 4 waves: wave0 = scalar row, waves1..3 = vector comps.
// Only the gate g crosses components (s-wave -> v-waves) via padded LDS (stride 33: conflict-free).
DEV void resblock_cw(int wave, const float* __restrict__ W7,
                     const float in[32], float out[32],
                     float* gbuf, int lane, bool active) {
  float t1[32];
  if (wave == 0) {
    linT<false>(W7 + 0*1024, in, t1);            // s1
    float gt[32];
    linT<false>(W7 + 2*1024, t1, gt);            // gate pre-act
    if (active) {
#pragma unroll
      for (int c = 0; c < 32; ++c) gbuf[lane*33+c] = sigmoidf(gt[c]);
    }
  } else {
    linT<false>(W7 + 1*1024, in, t1);            // v1
  }
  __syncthreads();
  if (wave == 0) {
    float s2[32];
#pragma unroll
    for (int c = 0; c < 32; ++c) s2[c] = t1[c] * sigmoidf(t1[c]);   // silu
    linT<false>(W7 + 3*1024, s2, out);
    linT<true >(W7 + 5*1024, in, out);           // skip
  } else {
    float v2[32];
#pragma unroll
    for (int c = 0; c < 32; ++c) v2[c] = t1[c] * gbuf[lane*33+c];
    linT<false>(W7 + 4*1024, v2, out);
    linT<true >(W7 + 6*1024, in, out);           // skip
  }
  __syncthreads();
}

// Per-node: diagonal branch output (dg_s,dg_v) + per-node precompute into scratch.
// Scratch layout per node (512 elems): A_s@0, A_v@32+32x, R_s@128, R_v@160+32x,
//                                      B0@256, Vr1@288+32x, Vr2@384+32x, B3@480
template<bool BF>
__global__ __launch_bounds__(256) void node_kernel(
    const float* __restrict__ node_s, const float* __restrict__ node_v,
    const float* __restrict__ tpw, const float* __restrict__ resw,
    void* __restrict__ wsN,
    float* __restrict__ dgs, float* __restrict__ dgv, int N)
{
  __shared__ float comm[6*2112];   // 6 slots [64][33]; also reused as [64][97] staging
  __shared__ float gbuf[2112];
  const int lane = threadIdx.x & 63;
  const int wave = threadIdx.x >> 6;
  const int nblk = blockIdx.x * 64;
  const int n = nblk + lane;
  const bool active = n < N;
  const int nrows = (N - nblk < 64) ? (N - nblk) : 64;

  const float* Wtp0 = tpw;
  const float* Wtp1 = tpw + 4096;

  // stage node_v rows ([n][32][3] f32) coalesced into LDS with stride-97 rows
  {
    const float4* s4 = reinterpret_cast<const float4*>(node_v + (size_t)nblk*96);
    int tot4 = nrows * 24;
    for (int i = threadIdx.x; i < tot4; i += 256) {
      int node = (4*i)/96; int r = 4*i - node*96;
      float4 q = s4[i];
      float* dp = &comm[node*97 + r];
      dp[0]=q.x; dp[1]=q.y; dp[2]=q.z; dp[3]=q.w;
    }
  }
  __syncthreads();

  float feat[32];
  if (wave == 0) {
    if (active) ld32f(node_s + (size_t)n*32, feat);
    else {
#pragma unroll
      for (int c = 0; c < 32; ++c) feat[c] = 0.f;
    }
  } else {
    const int x = wave - 1;
    if (active) {
#pragma unroll
      for (int c = 0; c < 32; ++c) feat[c] = comm[lane*97 + 3*c + x];
    } else {
#pragma unroll
      for (int c = 0; c < 32; ++c) feat[c] = 0.f;
    }
  }
  __syncthreads();   // comm about to be reused

  // ---- res3: ds,dv ----
  float dsv[32];
  resblock_cw(wave, resw + 3*7168, feat, dsv, gbuf, lane, active);

  // ---- tp0: left=(ds,dv), right=raw node feats ----
  float tpo[32];
  float vr2[32];
  if (wave != 0) {
    const int x = wave - 1;
    float vr1[32];
    linN(Wtp0 + 1*1024, feat, vr1);
    if (active) {
#pragma unroll
      for (int c = 0; c < 32; ++c) comm[x*2112 + lane*33 + c] = dsv[c];
#pragma unroll
      for (int c = 0; c < 32; ++c) comm[(3+x)*2112 + lane*33 + c] = vr1[c];
    }
  }
  __syncthreads();
  if (wave == 0) {
    float sr0[32], sr3[32];
    linN(Wtp0 + 0*1024, feat, sr0);
    linN(Wtp0 + 3*1024, feat, sr3);
#pragma unroll
    for (int c = 0; c < 32; ++c) {
      float a = comm[0*2112+lane*33+c]*comm[3*2112+lane*33+c]
              + comm[1*2112+lane*33+c]*comm[4*2112+lane*33+c]
              + comm[2*2112+lane*33+c]*comm[5*2112+lane*33+c];
      tpo[c] = dsv[c]*sr0[c] + a*INV_S3;
    }
    if (active) {
#pragma unroll
      for (int c = 0; c < 32; ++c) comm[0*2112+lane*33+c] = dsv[c];   // ds
#pragma unroll
      for (int c = 0; c < 32; ++c) comm[1*2112+lane*33+c] = sr3[c];
    }
  } else {
    linN(Wtp0 + 2*1024, feat, vr2);
  }
  __syncthreads();
  if (wave != 0) {
#pragma unroll
    for (int c = 0; c < 32; ++c)
      tpo[c] = comm[0*2112+lane*33+c]*vr2[c] + dsv[c]*comm[1*2112+lane*33+c];
  }

  // ---- res4 on tp output, res5 on raw, sum ----
  float eo[32];
  resblock_cw(wave, resw + 4*7168, tpo, eo, gbuf, lane, active);
  float qo[32];
  resblock_cw(wave, resw + 5*7168, feat, qo, gbuf, lane, active);
#pragma unroll
  for (int c = 0; c < 32; ++c) eo[c] += qo[c];

  // ---- store dg_s / dg_v (v staged through LDS stride-97 for coalesced writes) ----
  if (wave == 0) {
    if (active) st32f(dgs + (size_t)n*32, eo);
  } else {
    const int x = wave - 1;
    if (active) {
#pragma unroll
      for (int c = 0; c < 32; ++c) comm[lane*97 + 3*c + x] = eo[c];
    }
  }
  __syncthreads();
  {
    float4* d4 = reinterpret_cast<float4*>(dgv + (size_t)nblk*96);
    int tot4 = nrows * 24;
    for (int i = threadIdx.x; i < tot4; i += 256) {
      int node = (4*i)/96; int r = 4*i - node*96;
      const float* sp = &comm[node*97 + r];
      float4 q; q.x=sp[0]; q.y=sp[1]; q.z=sp[2]; q.w=sp[3];
      d4[i] = q;
    }
  }

  const size_t base = (size_t)n * 512;

  // ---- res0 -> A ----
  float ao[32];
  resblock_cw(wave, resw + 0*7168, feat, ao, gbuf, lane, active);
  if (active) {
    if (wave == 0) st_scr<BF>(wsN, base + 0, ao);
    else           st_scr<BF>(wsN, base + 32 + (size_t)(wave-1)*32, ao);
  }
  // ---- res2 -> R ----
  resblock_cw(wave, resw + 2*7168, feat, ao, gbuf, lane, active);
  if (active) {
    if (wave == 0) st_scr<BF>(wsN, base + 128, ao);
    else           st_scr<BF>(wsN, base + 160 + (size_t)(wave-1)*32, ao);
  }
  // ---- tp1 right-side linears on raw feats ----
  {
    float b[32];
    if (wave == 0) {
      linN(Wtp1 + 0*1024, feat, b);
      if (active) st_scr<BF>(wsN, base + 256, b);
      linN(Wtp1 + 3*1024, feat, b);
      if (active) st_scr<BF>(wsN, base + 480, b);
    } else {
      const size_t x = wave - 1;
      linN(Wtp1 + 1*1024, feat, b);
      if (active) st_scr<BF>(wsN, base + 288 + x*32, b);
      linN(Wtp1 + 2*1024, feat, b);
      if (active) st_scr<BF>(wsN, base + 384 + x*32, b);
    }
  }
}

// Per-edge: elementwise TP combine of A[dst] with B*[src], resblock(res_w[1]), +R[dst].
template<bool BF>
__global__ __launch_bounds__(256) void edge_kernel(
    const int* __restrict__ ei, const float* __restrict__ resw,
    const void* __restrict__ wsN,
    float* __restrict__ offs, float* __restrict__ offv, int E)
{
  __shared__ float gbuf[2112];
  __shared__ float vst[64*97];
  const int lane = threadIdx.x & 63;
  const int wave = threadIdx.x >> 6;
  const int eblk = blockIdx.x * 64;
  const int e = eblk + lane;
  const bool active = e < E;
  const int erows = (E - eblk < 64) ? (E - eblk) : 64;
  int src = 0, dst = 0;
  if (active) { src = ei[e]; dst = ei[E + e]; }
  const size_t bs = (size_t)src * 512;
  const size_t bd = (size_t)dst * 512;
  const float* Wres1 = resw + 1*7168;

  float t[32];
  if (wave == 0) {
    float a[32], b[32];
    ld_scr<BF>(wsN, bd + 0, a);        // A_s[dst]
    ld_scr<BF>(wsN, bs + 256, b);      // B0[src]
#pragma unroll
    for (int c = 0; c < 32; ++c) t[c] = a[c]*b[c];
#pragma unroll
    for (int x = 0; x < 3; ++x) {
      ld_scr<BF>(wsN, bd + 32 + (size_t)x*32, a);   // A_v[dst][x]
      ld_scr<BF>(wsN, bs + 288 + (size_t)x*32, b);  // Vr1[src][x]
#pragma unroll
      for (int c = 0; c < 32; ++c) t[c] = __builtin_fmaf(a[c]*INV_S3, b[c], t[c]);
    }
  } else {
    const size_t x = wave - 1;
    float sl[32], v2[32], vl[32], b3[32];
    ld_scr<BF>(wsN, bd + 0, sl);              // A_s[dst]
    ld_scr<BF>(wsN, bs + 384 + x*32, v2);     // Vr2[src][x]
    ld_scr<BF>(wsN, bd + 32 + x*32, vl);      // A_v[dst][x]
    ld_scr<BF>(wsN, bs + 480, b3);            // B3[src]
#pragma unroll
    for (int c = 0; c < 32; ++c) t[c] = sl[c]*v2[c] + vl[c]*b3[c];
  }

  float o[32];
  resblock_cw(wave, Wres1, t, o, gbuf, lane, active);

  if (wave == 0) {
    float r[32];
    ld_scr<BF>(wsN, bd + 128, r);             // R_s[dst]
#pragma unroll
    for (int c = 0; c < 32; ++c) o[c] += r[c];
    if (active) st32f(offs + (size_t)e*32, o);
  } else {
    const int x = wave - 1;
    float r[32];
    ld_scr<BF>(wsN, bd + 160 + (size_t)x*32, r);  // R_v[dst][x]
#pragma unroll
    for (int c = 0; c < 32; ++c) o[c] += r[c];
    if (active) {
#pragma unroll
      for (int c = 0; c < 32; ++c) vst[lane*97 + 3*c + x] = o[c];
    }
  }
  __syncthreads();
  {
    float4* d4 = reinterpret_cast<float4*>(offv + (size_t)eblk*96);
    int tot4 = erows * 24;
    for (int i = threadIdx.x; i < tot4; i += 256) {
      int row = (4*i)/96; int r = 4*i - row*96;
      const float* sp = &vst[row*97 + r];
      float4 q; q.x=sp[0]; q.y=sp[1]; q.z=sp[2]; q.w=sp[3];
      d4[i] = q;
    }
  }
}

extern "C" void kernel_launch(void* const* d_in, const int* in_sizes, int n_in,
                              void* d_out, int out_size, void* d_ws, size_t ws_size,
                              hipStream_t stream) {
  const float* node_s = (const float*)d_in[0];
  const float* node_v = (const float*)d_in[1];
  const float* tpw    = (const float*)d_in[2];
  const float* resw   = (const float*)d_in[3];
  const int*   ei     = (const int*)d_in[4];
  const int N = in_sizes[0] / 32;
  const int E = in_sizes[4] / 2;

  float* out  = (float*)d_out;
  float* dgs  = out;
  float* dgv  = out + (size_t)N*32;
  float* offs = out + (size_t)N*128;
  float* offv = offs + (size_t)E*32;

  const size_t need_f32 = (size_t)N * 512 * sizeof(float);
  const int nodeGrid = (N + 63) / 64;
  const int edgeGrid = (E + 63) / 64;

  if (ws_size >= need_f32) {
    node_kernel<false><<<nodeGrid, 256, 0, stream>>>(node_s, node_v, tpw, resw,
                                                     d_ws, dgs, dgv, N);
    edge_kernel<false><<<edgeGrid, 256, 0, stream>>>(ei, resw, d_ws, offs, offv, E);
  } else {
    node_kernel<true><<<nodeGrid, 256, 0, stream>>>(node_s, node_v, tpw, resw,
                                                    d_ws, dgs, dgv, N);
    edge_kernel<true><<<edgeGrid, 256, 0, stream>>>(ei, resw, d_ws, offs, offv, E);
  }
}

// Round 3
// 2151.052 us; speedup vs baseline: 34.0485x; 34.0485x over previous
//
#include <hip/hip_runtime.h>
#include <hip/hip_bf16.h>

#define DEV __device__ __forceinline__

typedef unsigned short u16;
typedef unsigned int u32;

constexpr float INV_C  = 0.17677669529663687f;   // 1/sqrt(32)
constexpr float INV_S3 = 0.5773502691896258f;    // 1/sqrt(3)

DEV float bf2f(u32 h) { return __uint_as_float(h << 16); }
DEV u32 f2bf_bits(float f) {
  u32 u = __float_as_uint(f);
  u += 0x7fffu + ((u >> 16) & 1u);
  return u >> 16;
}

DEV void ld32f(const float* __restrict__ p, float o[32]) {
#pragma unroll
  for (int i = 0; i < 8; ++i) {
    float4 q = reinterpret_cast<const float4*>(p)[i];
    o[4*i+0]=q.x; o[4*i+1]=q.y; o[4*i+2]=q.z; o[4*i+3]=q.w;
  }
}
DEV void st32f(float* __restrict__ p, const float o[32]) {
#pragma unroll
  for (int i = 0; i < 8; ++i) {
    float4 q; q.x=o[4*i+0]; q.y=o[4*i+1]; q.z=o[4*i+2]; q.w=o[4*i+3];
    reinterpret_cast<float4*>(p)[i] = q;
  }
}
DEV void ld32h(const u16* __restrict__ p, float o[32]) {
#pragma unroll
  for (int i = 0; i < 4; ++i) {
    uint4 q = reinterpret_cast<const uint4*>(p)[i];
    u32 w0=q.x, w1=q.y, w2=q.z, w3=q.w;
    o[8*i+0]=bf2f(w0 & 0xffffu); o[8*i+1]=bf2f(w0 >> 16);
    o[8*i+2]=bf2f(w1 & 0xffffu); o[8*i+3]=bf2f(w1 >> 16);
    o[8*i+4]=bf2f(w2 & 0xffffu); o[8*i+5]=bf2f(w2 >> 16);
    o[8*i+6]=bf2f(w3 & 0xffffu); o[8*i+7]=bf2f(w3 >> 16);
  }
}
DEV void st32h(u16* __restrict__ p, const float o[32]) {
#pragma unroll
  for (int i = 0; i < 16; ++i) {
    reinterpret_cast<u32*>(p)[i] = f2bf_bits(o[2*i]) | (f2bf_bits(o[2*i+1]) << 16);
  }
}

template<bool BF>
DEV void ld_scr(const void* __restrict__ ws, size_t off, float o[32]) {
  if (BF) ld32h((const u16*)ws + off, o);
  else    ld32f((const float*)ws + off, o);
}
template<bool BF>
DEV void st_scr(void* __restrict__ ws, size_t off, const float v[32]) {
  if (BF) st32h((u16*)ws + off, v);
  else    st32f((float*)ws + off, v);
}

// out[d] (+)= INV_C * sum_c in[c] * W[c*32+d]
// Limited unroll (4) keeps the scalar weight-load window bounded -> no spill.
template<bool ACC>
DEV void linT(const float* __restrict__ W, const float in[32], float out[32]) {
  float acc[32];
#pragma unroll
  for (int d = 0; d < 32; ++d) acc[d] = 0.f;
#pragma unroll 4
  for (int c = 0; c < 32; ++c) {
    const float ic = in[c];
#pragma unroll
    for (int d = 0; d < 32; ++d) acc[d] = __builtin_fmaf(ic, W[c*32+d], acc[d]);
  }
#pragma unroll
  for (int d = 0; d < 32; ++d) out[d] = ACC ? __builtin_fmaf(acc[d], INV_C, out[d]) : acc[d]*INV_C;
}
// out[u] = INV_C * sum_v in[v] * W[u*32+v]
DEV void linN(const float* __restrict__ W, const float in[32], float out[32]) {
#pragma unroll 4
  for (int u = 0; u < 32; ++u) {
    float a = 0.f;
#pragma unroll
    for (int v = 0; v < 32; ++v) a = __builtin_fmaf(in[v], W[u*32+v], a);
    out[u] = a * INV_C;
  }
}

DEV float sigmoidf(float x) { return 1.f / (1.f + __expf(-x)); }

// Resblock, wave0 = scalar row, waves1..3 = vector comps. Gate computed on wave0,
// shared through padded LDS (gsh, stride 33 -> conflict-free). Skip-linear is done
// FIRST so `in` dies early; barriers are outside all conditionals.
DEV void resblock_g(int wave, int lane, const float* __restrict__ W7,
                    const float in[32], float out[32], float* gsh) {
  float t1[32];
  linT<false>(W7 + (wave==0 ? 0 : 1)*1024, in, t1);     // s1 / v1
  linT<false>(W7 + (wave==0 ? 5 : 6)*1024, in, out);    // skip (in dies here)
  __syncthreads();                                      // gsh safe to overwrite
  float t2[32];
  if (wave == 0) {
    float g[32];
    linT<false>(W7 + 2*1024, t1, g);                    // gate pre-act
#pragma unroll
    for (int c = 0; c < 32; ++c) gsh[lane*33+c] = sigmoidf(g[c]);
#pragma unroll
    for (int c = 0; c < 32; ++c) t2[c] = t1[c] * sigmoidf(t1[c]);   // silu
  }
  __syncthreads();
  if (wave != 0) {
#pragma unroll
    for (int c = 0; c < 32; ++c) t2[c] = t1[c] * gsh[lane*33+c];
  }
  linT<true>(W7 + (wave==0 ? 3 : 4)*1024, t2, out);     // lin2, accumulate onto skip
}

// Per-node: diagonal branch output (dg_s,dg_v) + per-node precompute into scratch.
// Scratch per node (512 elems): A_s@0, A_v@32+32x, R_s@128, R_v@160+32x,
//                               B0@256, Vr1@288+32x, Vr2@384+32x, B3@480
template<bool BF>
__global__ __launch_bounds__(256, 2) void node_kernel(
    const float* __restrict__ node_s, const float* __restrict__ node_v,
    const float* __restrict__ tpw, const float* __restrict__ resw,
    void* __restrict__ wsN,
    float* __restrict__ dgs, float* __restrict__ dgv, int N)
{
  __shared__ float comm[6*2112];   // 6 slots [64][33]; reused as [64][97] staging
  __shared__ float gsh[2112];
  const int lane = threadIdx.x & 63;
  const int wave = threadIdx.x >> 6;
  const int nblk = blockIdx.x * 64;
  const int n = nblk + lane;
  const bool active = n < N;
  const int nrows = (N - nblk < 64) ? (N - nblk) : 64;

  const float* Wtp0 = tpw;
  const float* Wtp1 = tpw + 4096;

  // stage node_v rows ([n][32][3] f32) coalesced into LDS stride-97 rows
  {
    const float4* s4 = reinterpret_cast<const float4*>(node_v + (size_t)nblk*96);
    int tot4 = nrows * 24;
    for (int i = threadIdx.x; i < tot4; i += 256) {
      int node = (4*i)/96; int r = 4*i - node*96;
      float4 q = s4[i];
      float* dp = &comm[node*97 + r];
      dp[0]=q.x; dp[1]=q.y; dp[2]=q.z; dp[3]=q.w;
    }
  }
  __syncthreads();

  float feat[32];
  if (wave == 0) {
    if (active) ld32f(node_s + (size_t)n*32, feat);
    else {
#pragma unroll
      for (int c = 0; c < 32; ++c) feat[c] = 0.f;
    }
  } else {
    const int x = wave - 1;
    if (active) {
#pragma unroll
      for (int c = 0; c < 32; ++c) feat[c] = comm[lane*97 + 3*c + x];
    } else {
#pragma unroll
      for (int c = 0; c < 32; ++c) feat[c] = 0.f;
    }
  }
  __syncthreads();   // comm about to be reused

  // ---- res3: ds,dv ----
  float dsv[32];
  resblock_g(wave, lane, resw + 3*7168, feat, dsv, gsh);

  // ---- tp0: left=(ds,dv), right=raw node feats ----
  float tpo[32];
  if (wave != 0) {
    const int x = wave - 1;
    float vr1[32];
    linN(Wtp0 + 1*1024, feat, vr1);
#pragma unroll
    for (int c = 0; c < 32; ++c) comm[x*2112 + lane*33 + c] = dsv[c];
#pragma unroll
    for (int c = 0; c < 32; ++c) comm[(3+x)*2112 + lane*33 + c] = vr1[c];
  }
  __syncthreads();
  if (wave == 0) {
    float sr0[32];
    linN(Wtp0 + 0*1024, feat, sr0);
#pragma unroll
    for (int c = 0; c < 32; ++c) {
      float a = comm[0*2112+lane*33+c]*comm[3*2112+lane*33+c]
              + comm[1*2112+lane*33+c]*comm[4*2112+lane*33+c]
              + comm[2*2112+lane*33+c]*comm[5*2112+lane*33+c];
      tpo[c] = dsv[c]*sr0[c] + a*INV_S3;
    }
    float sr3[32];
    linN(Wtp0 + 3*1024, feat, sr3);
#pragma unroll
    for (int c = 0; c < 32; ++c) comm[0*2112+lane*33+c] = dsv[c];   // ds
#pragma unroll
    for (int c = 0; c < 32; ++c) comm[1*2112+lane*33+c] = sr3[c];
  }
  __syncthreads();
  if (wave != 0) {
    float vr2[32];
    linN(Wtp0 + 2*1024, feat, vr2);
#pragma unroll
    for (int c = 0; c < 32; ++c)
      tpo[c] = comm[0*2112+lane*33+c]*vr2[c] + dsv[c]*comm[1*2112+lane*33+c];
  }

  // ---- res4 on tp output, res5 on raw, sum ----
  float eo[32];
  resblock_g(wave, lane, resw + 4*7168, tpo, eo, gsh);
  {
    float qo[32];
    resblock_g(wave, lane, resw + 5*7168, feat, qo, gsh);
#pragma unroll
    for (int c = 0; c < 32; ++c) eo[c] += qo[c];
  }

  // ---- store dg_s / dg_v (v staged through LDS stride-97 for coalesced writes) ----
  if (wave == 0) {
    if (active) st32f(dgs + (size_t)n*32, eo);
  } else {
    const int x = wave - 1;
#pragma unroll
    for (int c = 0; c < 32; ++c) comm[lane*97 + 3*c + x] = eo[c];
  }
  __syncthreads();
  {
    float4* d4 = reinterpret_cast<float4*>(dgv + (size_t)nblk*96);
    int tot4 = nrows * 24;
    for (int i = threadIdx.x; i < tot4; i += 256) {
      int node = (4*i)/96; int r = 4*i - node*96;
      const float* sp = &comm[node*97 + r];
      float4 q; q.x=sp[0]; q.y=sp[1]; q.z=sp[2]; q.w=sp[3];
      d4[i] = q;
    }
  }

  const size_t base = (size_t)n * 512;

  // ---- res0 -> A ----
  {
    float ao[32];
    resblock_g(wave, lane, resw + 0*7168, feat, ao, gsh);
    if (active) {
      if (wave == 0) st_scr<BF>(wsN, base + 0, ao);
      else           st_scr<BF>(wsN, base + 32 + (size_t)(wave-1)*32, ao);
    }
  }
  // ---- res2 -> R ----
  {
    float ao[32];
    resblock_g(wave, lane, resw + 2*7168, feat, ao, gsh);
    if (active) {
      if (wave == 0) st_scr<BF>(wsN, base + 128, ao);
      else           st_scr<BF>(wsN, base + 160 + (size_t)(wave-1)*32, ao);
    }
  }
  // ---- tp1 right-side linears on raw feats ----
  {
    float b[32];
    if (wave == 0) {
      linN(Wtp1 + 0*1024, feat, b);
      if (active) st_scr<BF>(wsN, base + 256, b);
      linN(Wtp1 + 3*1024, feat, b);
      if (active) st_scr<BF>(wsN, base + 480, b);
    } else {
      const size_t x = wave - 1;
      linN(Wtp1 + 1*1024, feat, b);
      if (active) st_scr<BF>(wsN, base + 288 + x*32, b);
      linN(Wtp1 + 2*1024, feat, b);
      if (active) st_scr<BF>(wsN, base + 384 + x*32, b);
    }
  }
}

// Per-edge: elementwise TP combine of A[dst] with B*[src], resblock(res_w[1]), +R[dst].
template<bool BF>
__global__ __launch_bounds__(256, 2) void edge_kernel(
    const int* __restrict__ ei, const float* __restrict__ resw,
    const void* __restrict__ wsN,
    float* __restrict__ offs, float* __restrict__ offv, int E)
{
  __shared__ float gsh[2112];
  __shared__ float vst[64*97];
  const int lane = threadIdx.x & 63;
  const int wave = threadIdx.x >> 6;
  const int eblk = blockIdx.x * 64;
  const int e = eblk + lane;
  const bool active = e < E;
  const int erows = (E - eblk < 64) ? (E - eblk) : 64;
  int src = 0, dst = 0;
  if (active) { src = ei[e]; dst = ei[E + e]; }
  const size_t bs = (size_t)src * 512;
  const size_t bd = (size_t)dst * 512;
  const float* Wres1 = resw + 1*7168;

  float t[32];
  if (wave == 0) {
    float a[32], b[32];
    ld_scr<BF>(wsN, bd + 0, a);        // A_s[dst]
    ld_scr<BF>(wsN, bs + 256, b);      // B0[src]
#pragma unroll
    for (int c = 0; c < 32; ++c) t[c] = a[c]*b[c];
#pragma unroll
    for (int x = 0; x < 3; ++x) {
      ld_scr<BF>(wsN, bd + 32 + (size_t)x*32, a);   // A_v[dst][x]
      ld_scr<BF>(wsN, bs + 288 + (size_t)x*32, b);  // Vr1[src][x]
#pragma unroll
      for (int c = 0; c < 32; ++c) t[c] = __builtin_fmaf(a[c]*INV_S3, b[c], t[c]);
    }
  } else {
    const size_t x = wave - 1;
    float a[32], b[32];
    ld_scr<BF>(wsN, bd + 0, a);               // A_s[dst]
    ld_scr<BF>(wsN, bs + 384 + x*32, b);      // Vr2[src][x]
#pragma unroll
    for (int c = 0; c < 32; ++c) t[c] = a[c]*b[c];
    ld_scr<BF>(wsN, bd + 32 + x*32, a);       // A_v[dst][x]
    ld_scr<BF>(wsN, bs + 480, b);             // B3[src]
#pragma unroll
    for (int c = 0; c < 32; ++c) t[c] = __builtin_fmaf(a[c], b[c], t[c]);
  }

  float o[32];
  resblock_g(wave, lane, Wres1, t, o, gsh);

  if (wave == 0) {
    float r[32];
    ld_scr<BF>(wsN, bd + 128, r);             // R_s[dst]
#pragma unroll
    for (int c = 0; c < 32; ++c) o[c] += r[c];
    if (active) st32f(offs + (size_t)e*32, o);
  } else {
    const int x = wave - 1;
    float r[32];
    ld_scr<BF>(wsN, bd + 160 + (size_t)x*32, r);  // R_v[dst][x]
#pragma unroll
    for (int c = 0; c < 32; ++c) o[c] += r[c];
#pragma unroll
    for (int c = 0; c < 32; ++c) vst[lane*97 + 3*c + x] = o[c];
  }
  __syncthreads();
  {
    float4* d4 = reinterpret_cast<float4*>(offv + (size_t)eblk*96);
    int tot4 = erows * 24;
    for (int i = threadIdx.x; i < tot4; i += 256) {
      int row = (4*i)/96; int r = 4*i - row*96;
      const float* sp = &vst[row*97 + r];
      float4 q; q.x=sp[0]; q.y=sp[1]; q.z=sp[2]; q.w=sp[3];
      d4[i] = q;
    }
  }
}

extern "C" void kernel_launch(void* const* d_in, const int* in_sizes, int n_in,
                              void* d_out, int out_size, void* d_ws, size_t ws_size,
                              hipStream_t stream) {
  const float* node_s = (const float*)d_in[0];
  const float* node_v = (const float*)d_in[1];
  const float* tpw    = (const float*)d_in[2];
  const float* resw   = (const float*)d_in[3];
  const int*   ei     = (const int*)d_in[4];
  const int N = in_sizes[0] / 32;
  const int E = in_sizes[4] / 2;

  float* out  = (float*)d_out;
  float* dgs  = out;
  float* dgv  = out + (size_t)N*32;
  float* offs = out + (size_t)N*128;
  float* offv = offs + (size_t)E*32;

  const size_t need_f32 = (size_t)N * 512 * sizeof(float);
  const int nodeGrid = (N + 63) / 64;
  const int edgeGrid = (E + 63) / 64;

  if (ws_size >= need_f32) {
    node_kernel<false><<<nodeGrid, 256, 0, stream>>>(node_s, node_v, tpw, resw,
                                                     d_ws, dgs, dgv, N);
    edge_kernel<false><<<edgeGrid, 256, 0, stream>>>(ei, resw, d_ws, offs, offv, E);
  } else {
    node_kernel<true><<<nodeGrid, 256, 0, stream>>>(node_s, node_v, tpw, resw,
                                                    d_ws, dgs, dgv, N);
    edge_kernel<true><<<edgeGrid, 256, 0, stream>>>(ei, resw, d_ws, offs, offv, E);
  }
}